// Round 1
// baseline (286.702 us; speedup 1.0000x reference)
//
#include <hip/hip_runtime.h>

#define B_    8
#define D_IN  256
#define D_HID 1024
#define D_OUT 40000       // = 200*200
#define CHW   10240000    // 256*200*200
#define TOT4  20480000    // 8*CHW/4
#define CHW4  2560000     // CHW/4
#define HW4   10000       // 40000/4

// Kernel 1: hT[j*8+b] = leakyrelu(loc[b,:] @ W1[:,j] + b1[j])
__global__ void mlp1_kernel(const float* __restrict__ loc,
                            const float* __restrict__ W1,
                            const float* __restrict__ b1,
                            float* __restrict__ hT) {
    int tid = blockIdx.x * blockDim.x + threadIdx.x;   // 8192 threads
    if (tid >= B_ * D_HID) return;
    int b = tid >> 10;          // tid / 1024
    int j = tid & 1023;
    float acc = b1[j];
    #pragma unroll 8
    for (int k = 0; k < D_IN; ++k) {
        acc += loc[b * D_IN + k] * W1[k * D_HID + j];
    }
    acc = (acc >= 0.0f) ? acc : 0.1f * acc;
    hT[j * B_ + b] = acc;
}

// Kernel 2: wmap[b*40000+j] = 1 + (h[b,:] @ W2[:,j] + b2[j])
// One thread per column j; W2 reads coalesced (consecutive j -> consecutive addr).
// hT reads are wave-uniform -> scalar loads (contiguous 8 floats per k).
__global__ void mlp2_kernel(const float* __restrict__ hT,
                            const float* __restrict__ W2,
                            const float* __restrict__ b2,
                            float* __restrict__ wmap) {
    int j = blockIdx.x * blockDim.x + threadIdx.x;
    if (j >= D_OUT) return;
    float bias = b2[j];
    float acc[B_];
    #pragma unroll
    for (int b = 0; b < B_; ++b) acc[b] = bias;
    #pragma unroll 4
    for (int k = 0; k < D_HID; ++k) {
        float wv = W2[k * D_OUT + j];
        #pragma unroll
        for (int b = 0; b < B_; ++b) {
            acc[b] += hT[k * B_ + b] * wv;
        }
    }
    #pragma unroll
    for (int b = 0; b < B_; ++b) {
        wmap[b * D_OUT + j] = 1.0f + acc[b];
    }
}

// Kernel 3: out = x * wmap_broadcast  (wmap already holds 1+w)
__global__ void scale_kernel(const float* __restrict__ x,
                             const float* __restrict__ wmap,
                             float* __restrict__ out) {
    const float4* __restrict__ x4 = (const float4*)x;
    const float4* __restrict__ w4 = (const float4*)wmap;
    float4* __restrict__ o4 = (float4*)out;
    int stride = gridDim.x * blockDim.x;
    for (int i = blockIdx.x * blockDim.x + threadIdx.x; i < TOT4; i += stride) {
        unsigned int b  = (unsigned int)i / CHW4;       // magic-mul div
        unsigned int p4 = (unsigned int)i % HW4;        // spatial vec4 index
        float4 xv = x4[i];
        float4 wv = w4[b * HW4 + p4];                   // L2-resident (1.28 MB)
        float4 ov;
        ov.x = xv.x * wv.x;
        ov.y = xv.y * wv.y;
        ov.z = xv.z * wv.z;
        ov.w = xv.w * wv.w;
        o4[i] = ov;
    }
}

extern "C" void kernel_launch(void* const* d_in, const int* in_sizes, int n_in,
                              void* d_out, int out_size, void* d_ws, size_t ws_size,
                              hipStream_t stream) {
    const float* x   = (const float*)d_in[0];
    const float* loc = (const float*)d_in[1];
    const float* W1  = (const float*)d_in[2];
    const float* b1  = (const float*)d_in[3];
    const float* W2  = (const float*)d_in[4];
    const float* b2  = (const float*)d_in[5];
    float* out = (float*)d_out;

    float* hT   = (float*)d_ws;                       // 8192 floats = 32 KB
    float* wmap = (float*)((char*)d_ws + 32768);      // 320000 floats = 1.28 MB

    // K1: 8192 threads
    mlp1_kernel<<<32, 256, 0, stream>>>(loc, W1, b1, hT);
    // K2: 40000 columns
    mlp2_kernel<<<(D_OUT + 255) / 256, 256, 0, stream>>>(hT, W2, b2, wmap);
    // K3: elementwise, grid-stride
    scale_kernel<<<2048, 256, 0, stream>>>(x, wmap, out);
}

// Round 2
// 172.485 us; speedup vs baseline: 1.6622x; 1.6622x over previous
//
#include <hip/hip_runtime.h>

#define B_    8
#define D_IN  256
#define D_HID 1024
#define D_OUT 40000       // = 200*200
#define CHW4  2560000     // 256*200*200/4
#define TOT4  20480000    // 8*CHW4
#define HW4   10000       // 40000/4

typedef float f32x4 __attribute__((ext_vector_type(4)));

// Kernel 1: hT[j*8+b] = leakyrelu(loc[b,:] @ W1[:,j] + b1[j])
__global__ void mlp1_kernel(const float* __restrict__ loc,
                            const float* __restrict__ W1,
                            const float* __restrict__ b1,
                            float* __restrict__ hT) {
    int tid = blockIdx.x * blockDim.x + threadIdx.x;   // 8192 threads
    if (tid >= B_ * D_HID) return;
    int b = tid >> 10;
    int j = tid & 1023;
    float acc = b1[j];
    #pragma unroll 8
    for (int k = 0; k < D_IN; ++k) {
        acc += loc[b * D_IN + k] * W1[k * D_HID + j];
    }
    acc = (acc >= 0.0f) ? acc : 0.1f * acc;
    hT[j * B_ + b] = acc;
}

// Kernel 2a: split-K partial GEMM. partial[(ks*8+b)*D_OUT + j] = sum over k-chunk.
__global__ void mlp2_partial_kernel(const float* __restrict__ hT,
                                    const float* __restrict__ W2,
                                    float* __restrict__ partial,
                                    int chunk) {
    int j = blockIdx.x * blockDim.x + threadIdx.x;
    if (j >= D_OUT) return;
    int ks = blockIdx.y;
    int k0 = ks * chunk;
    float acc[B_];
    #pragma unroll
    for (int b = 0; b < B_; ++b) acc[b] = 0.0f;
    #pragma unroll 4
    for (int kk = 0; kk < chunk; ++kk) {
        int k = k0 + kk;
        float wv = W2[k * D_OUT + j];          // coalesced across lanes
        #pragma unroll
        for (int b = 0; b < B_; ++b) {
            acc[b] += hT[k * B_ + b] * wv;     // wave-uniform -> scalar loads
        }
    }
    #pragma unroll
    for (int b = 0; b < B_; ++b) {
        partial[(ks * B_ + b) * D_OUT + j] = acc[b];
    }
}

// Kernel 2b: reduce partials, add bias, write 1+w
__global__ void mlp2_reduce_kernel(const float* __restrict__ partial,
                                   const float* __restrict__ b2,
                                   float* __restrict__ wmap,
                                   int KS) {
    int t = blockIdx.x * blockDim.x + threadIdx.x;   // over 320000
    if (t >= B_ * D_OUT) return;
    int b = t / D_OUT;
    int j = t - b * D_OUT;
    float s = 1.0f + b2[j];
    for (int ks = 0; ks < KS; ++ks) {
        s += partial[(ks * B_ + b) * D_OUT + j];     // coalesced per ks-plane
    }
    wmap[b * D_OUT + j] = s;
}

// Kernel 3: out = x * wmap_broadcast. Non-temporal on the streamed 655 MB so
// wmap (1.28 MB) stays L2-resident.
__global__ void scale_kernel(const float* __restrict__ x,
                             const float* __restrict__ wmap,
                             float* __restrict__ out) {
    const f32x4* __restrict__ x4 = (const f32x4*)x;
    const f32x4* __restrict__ w4 = (const f32x4*)wmap;
    f32x4* __restrict__ o4 = (f32x4*)out;
    int stride = gridDim.x * blockDim.x;
    for (int i = blockIdx.x * blockDim.x + threadIdx.x; i < TOT4; i += stride) {
        unsigned int b  = (unsigned int)i / CHW4;
        unsigned int p4 = (unsigned int)i % HW4;     // CHW4 multiple of HW4
        f32x4 xv = __builtin_nontemporal_load(&x4[i]);
        f32x4 wv = w4[b * HW4 + p4];                 // L2-resident
        __builtin_nontemporal_store(xv * wv, &o4[i]);
    }
}

extern "C" void kernel_launch(void* const* d_in, const int* in_sizes, int n_in,
                              void* d_out, int out_size, void* d_ws, size_t ws_size,
                              hipStream_t stream) {
    const float* x   = (const float*)d_in[0];
    const float* loc = (const float*)d_in[1];
    const float* W1  = (const float*)d_in[2];
    const float* b1  = (const float*)d_in[3];
    const float* W2  = (const float*)d_in[4];
    const float* b2  = (const float*)d_in[5];
    float* out = (float*)d_out;

    float* hT   = (float*)d_ws;                            // 32 KB
    float* wmap = (float*)((char*)d_ws + 32768);           // 1.28 MB
    float* partial = (float*)((char*)d_ws + 32768 + 1280000);

    // Pick largest split that fits the workspace (deterministic per-session).
    size_t base = 32768 + 1280000;
    int KS = 1;
    for (int cand = 16; cand >= 1; cand >>= 1) {
        if (base + (size_t)cand * B_ * D_OUT * sizeof(float) <= ws_size) { KS = cand; break; }
    }
    int chunk = D_HID / KS;

    mlp1_kernel<<<32, 256, 0, stream>>>(loc, W1, b1, hT);

    dim3 g2((D_OUT + 255) / 256, KS);
    mlp2_partial_kernel<<<g2, 256, 0, stream>>>(hT, W2, partial, chunk);

    mlp2_reduce_kernel<<<(B_ * D_OUT + 255) / 256, 256, 0, stream>>>(partial, b2, wmap, KS);

    scale_kernel<<<2048, 256, 0, stream>>>(x, wmap, out);
}